// Round 1
// baseline (878.093 us; speedup 1.0000x reference)
//
#include <hip/hip_runtime.h>
#include <hip/hip_bf16.h>

// Sizes from the reference
#define N_NODES 65536
#define CFCH 16
#define L0LEN 4097
#define NSFC 2
#define LATD 128
#define HIDD 512
#define BATCH 16
#define NROWS (CFCH * L0LEN * NSFC)   // 131104
#define L1LEN 16385

__device__ __forceinline__ float fast_tanh(float x) {
    float ax = fabsf(x);
    float e = __expf(-2.0f * ax);          // v_exp_f32 path
    float r = (1.0f - e) / (1.0f + e);     // in [0,1), stable for all ax
    return copysignf(r, x);
}

// ---------------- fc1: h1T[j*16+b] = tanh(x[b,:]·W1[j,:] + b1[j]) ----------------
__global__ void fc1_kernel(const float* __restrict__ x, const float* __restrict__ W1,
                           const float* __restrict__ b1, float* __restrict__ h1T) {
    int tid = blockIdx.x * 256 + threadIdx.x;   // 8192 threads
    int b = tid & 15;
    int j = tid >> 4;
    const float* xr = x + b * LATD;
    const float* wr = W1 + j * LATD;
    float acc = 0.f;
#pragma unroll 8
    for (int k = 0; k < LATD; ++k) acc = fmaf(xr[k], wr[k], acc);
    h1T[(j << 4) + b] = fast_tanh(acc + b1[j]);
}

// ---------------- fc2: h2 = tanh(h1 @ W2^T + b2), scattered to [sfc][b][c][l] ----------------
__global__ void __launch_bounds__(256) fc2_kernel(const float* __restrict__ W2,
                                                  const float* __restrict__ b2,
                                                  const float* __restrict__ h1T,
                                                  float* __restrict__ h2) {
    __shared__ float hS[HIDD * 16];   // 32 KB, layout [k][b]
    for (int idx = threadIdx.x; idx < HIDD * 16; idx += 256) hS[idx] = h1T[idx];
    __syncthreads();

    int j = blockIdx.x * 256 + threadIdx.x;
    if (j >= NROWS) j = NROWS - 1;    // clamp (uniform control flow; dup writes same value)

    const float4* wrow = (const float4*)(W2 + (size_t)j * HIDD);
    float acc[16];
#pragma unroll
    for (int b = 0; b < 16; ++b) acc[b] = 0.f;

    for (int k0 = 0; k0 < HIDD / 8; ++k0) {
        float4 wa = wrow[k0 * 2];
        float4 wb = wrow[k0 * 2 + 1];
        float w[8] = {wa.x, wa.y, wa.z, wa.w, wb.x, wb.y, wb.z, wb.w};
#pragma unroll
        for (int kk = 0; kk < 8; ++kk) {
            const float4* hp = (const float4*)&hS[((k0 * 8 + kk) << 4)];
            float4 ha = hp[0], hb = hp[1], hc = hp[2], hd = hp[3];
            float wv = w[kk];
            acc[0]  = fmaf(wv, ha.x, acc[0]);
            acc[1]  = fmaf(wv, ha.y, acc[1]);
            acc[2]  = fmaf(wv, ha.z, acc[2]);
            acc[3]  = fmaf(wv, ha.w, acc[3]);
            acc[4]  = fmaf(wv, hb.x, acc[4]);
            acc[5]  = fmaf(wv, hb.y, acc[5]);
            acc[6]  = fmaf(wv, hb.z, acc[6]);
            acc[7]  = fmaf(wv, hb.w, acc[7]);
            acc[8]  = fmaf(wv, hc.x, acc[8]);
            acc[9]  = fmaf(wv, hc.y, acc[9]);
            acc[10] = fmaf(wv, hc.z, acc[10]);
            acc[11] = fmaf(wv, hc.w, acc[11]);
            acc[12] = fmaf(wv, hd.x, acc[12]);
            acc[13] = fmaf(wv, hd.y, acc[13]);
            acc[14] = fmaf(wv, hd.z, acc[14]);
            acc[15] = fmaf(wv, hd.w, acc[15]);
        }
    }
    float bias = b2[j];
    int i = j & 1;
    int s = j >> 1;
    int c = s / L0LEN;
    int l = s - c * L0LEN;
#pragma unroll
    for (int b = 0; b < 16; ++b) {
        h2[(((size_t)(i * 16 + b) * CFCH + c) * L0LEN) + l] = fast_tanh(acc[b] + bias);
    }
}

// ---------------- conv0: ConvTranspose1d(16->16, K=32, s=4, p=16, op=1) + tanh ----------------
// out[o] = sum_ci sum_t w[ci][co][r+4t]*in[ci][q0-t],  r=(o+16)&3, q0=(o+16)>>2
__global__ void __launch_bounds__(256) conv0_kernel(const float* __restrict__ h2,
                                                    const float* __restrict__ ctw0,
                                                    const float* __restrict__ ctb0,
                                                    float* __restrict__ t0) {
    __shared__ float wL[16 * 4 * 132];  // [(co*4+r)][ci*8+t], stride 132 (pad: bank spread)
    __shared__ float inS[16 * 40];      // [ci][q window of 40]
    int i = blockIdx.z, bb = blockIdx.y, bx = blockIdx.x;
    int tid = threadIdx.x;

    for (int idx = tid; idx < 16 * 4 * 128; idx += 256) {
        int cor = idx >> 7;       // co*4+r
        int rem = idx & 127;      // ci*8+t
        int co = cor >> 2, r = cor & 3;
        int ci = rem >> 3, t = rem & 7;
        wL[cor * 132 + rem] = ctw0[(((i * 16 + ci) * 16 + co) << 5) + r + (t << 2)];
    }
    int o0 = bx << 7;                 // 128 outputs per (block, co)
    int q00 = (o0 >> 2) + 4;
    int qbase = q00 - 8;              // multiple of 4
    const float* hin = h2 + (size_t)(i * 16 + bb) * CFCH * L0LEN;
    for (int idx = tid; idx < 16 * 40; idx += 256) {
        int ci = idx / 40, x2 = idx - ci * 40;
        int q = qbase + x2;
        inS[idx] = (q >= 0 && q < L0LEN) ? hin[ci * L0LEN + q] : 0.f;
    }
    __syncthreads();

    int co = tid >> 4, chunk = (tid >> 2) & 3, r = tid & 3;
    float acc[8];
#pragma unroll
    for (int u = 0; u < 8; ++u) acc[u] = 0.f;
    const float* wrow = &wL[(co * 4 + r) * 132];

    for (int ci = 0; ci < 16; ++ci) {
        const float4* xp = (const float4*)&inS[ci * 40 + (chunk << 3)];
        float4 xa = xp[0], xb = xp[1], xc = xp[2], xd = xp[3];
        float xin[16] = {xa.x, xa.y, xa.z, xa.w, xb.x, xb.y, xb.z, xb.w,
                         xc.x, xc.y, xc.z, xc.w, xd.x, xd.y, xd.z, xd.w};
        const float4* wp = (const float4*)(wrow + (ci << 3));
        float4 wlo = wp[0], whi = wp[1];
        float wv[8] = {wlo.x, wlo.y, wlo.z, wlo.w, whi.x, whi.y, whi.z, whi.w};
#pragma unroll
        for (int t = 0; t < 8; ++t)
#pragma unroll
            for (int u = 0; u < 8; ++u)
                acc[u] = fmaf(wv[t], xin[u - t + 8], acc[u]);
    }
    float bias = ctb0[i * 16 + co];
    float* dst = t0 + ((size_t)(i * 16 + bb) * 16 + co) * L1LEN;
#pragma unroll
    for (int u = 0; u < 8; ++u) {
        int o = o0 + (((chunk << 3) + u) << 2) + r;
        if (o < L1LEN) dst[o] = fast_tanh(acc[u] + bias);
    }
}

// ---------------- conv1: ConvTranspose1d(16->1, K=32, s=4, p=16, op=0) + tanh ----------------
__global__ void __launch_bounds__(256) conv1_kernel(const float* __restrict__ t0,
                                                    const float* __restrict__ ctw1,
                                                    const float* __restrict__ ctb1,
                                                    float* __restrict__ t1) {
    __shared__ float wL[4 * 136];     // [r][ci*8+t], stride 136 (16B aligned, bank spread)
    __shared__ float inS[16 * 520];   // [ci][q window of 520]
    int i = blockIdx.z, bb = blockIdx.y, bx = blockIdx.x;
    int tid = threadIdx.x;

    for (int idx = tid; idx < 512; idx += 256) {
        int r = idx >> 7;
        int rem = idx & 127;          // ci*8+t
        int ci = rem >> 3, t = rem & 7;
        wL[r * 136 + rem] = ctw1[((i * 16 + ci) << 5) + r + (t << 2)];
    }
    int o0 = bx << 11;                // 2048 outputs per block
    int q00 = (o0 >> 2) + 4;
    int qbase = q00 - 8;
    const float* tin = t0 + (size_t)(i * 16 + bb) * 16 * L1LEN;
    for (int idx = tid; idx < 16 * 520; idx += 256) {
        int ci = idx / 520, x2 = idx - ci * 520;
        int q = qbase + x2;
        inS[idx] = (q >= 0 && q < L1LEN) ? tin[ci * L1LEN + q] : 0.f;
    }
    __syncthreads();

    int chunk = tid >> 2, r = tid & 3;
    float acc[8];
#pragma unroll
    for (int u = 0; u < 8; ++u) acc[u] = 0.f;
    const float* wrow = &wL[r * 136];

    for (int ci = 0; ci < 16; ++ci) {
        const float4* xp = (const float4*)&inS[ci * 520 + (chunk << 3)];
        float4 xa = xp[0], xb = xp[1], xc = xp[2], xd = xp[3];
        float xin[16] = {xa.x, xa.y, xa.z, xa.w, xb.x, xb.y, xb.z, xb.w,
                         xc.x, xc.y, xc.z, xc.w, xd.x, xd.y, xd.z, xd.w};
        const float4* wp = (const float4*)(wrow + (ci << 3));
        float4 wlo = wp[0], whi = wp[1];
        float wv[8] = {wlo.x, wlo.y, wlo.z, wlo.w, whi.x, whi.y, whi.z, whi.w};
#pragma unroll
        for (int t = 0; t < 8; ++t)
#pragma unroll
            for (int u = 0; u < 8; ++u)
                acc[u] = fmaf(wv[t], xin[u - t + 8], acc[u]);
    }
    float bias = ctb1[i];
    float* dst = t1 + (size_t)(i * 16 + bb) * (size_t)N_NODES;
#pragma unroll
    for (int u = 0; u < 8; ++u) {
        int o = o0 + (((chunk << 3) + u) << 2) + r;
        dst[o] = fast_tanh(acc[u] + bias);
    }
}

// ---------------- gather + per-sfc NN + final NN + output linear ----------------
__global__ void final_kernel(const float* __restrict__ t1,
                             const float* __restrict__ sps_w, const float* __restrict__ sps_b,
                             const float* __restrict__ final_w, const float* __restrict__ final_b,
                             const float* __restrict__ out_w, const float* __restrict__ out_b,
                             const int* __restrict__ ord_idx, const int* __restrict__ plus_idx,
                             const int* __restrict__ minus_idx, float* __restrict__ out) {
    int g = blockIdx.x * 256 + threadIdx.x;   // 16*65536 threads
    int b = g >> 16;
    int n = g & 65535;
    float z[2];
#pragma unroll
    for (int i = 0; i < 2; ++i) {
        int base = i * N_NODES + n;
        int im = minus_idx[base], io = ord_idx[base], ip = plus_idx[base];
        const float* tb = t1 + ((size_t)(i * 16 + b) << 16);
        float vm = tb[im], vo = tb[io], vp = tb[ip];
        const float* sw = sps_w + (size_t)base * 3;
        float s = fmaf(vm, sw[0], fmaf(vo, sw[1], vp * sw[2])) + sps_b[base];
        z[i] = fast_tanh(s);
    }
    float zz = fast_tanh(fmaf(z[0], final_w[n * 2], fmaf(z[1], final_w[n * 2 + 1], final_b[n])));
    out[g] = fmaf(zz, out_w[n], out_b[n]);
}

extern "C" void kernel_launch(void* const* d_in, const int* in_sizes, int n_in,
                              void* d_out, int out_size, void* d_ws, size_t ws_size,
                              hipStream_t stream) {
    const float* x       = (const float*)d_in[0];
    const float* W1      = (const float*)d_in[1];
    const float* b1      = (const float*)d_in[2];
    const float* W2      = (const float*)d_in[3];
    const float* b2      = (const float*)d_in[4];
    const float* ctw0    = (const float*)d_in[5];
    const float* ctb0    = (const float*)d_in[6];
    const float* ctw1    = (const float*)d_in[7];
    const float* ctb1    = (const float*)d_in[8];
    const float* sps_w   = (const float*)d_in[9];
    const float* sps_b   = (const float*)d_in[10];
    const float* final_w = (const float*)d_in[11];
    const float* final_b = (const float*)d_in[12];
    const float* out_w   = (const float*)d_in[13];
    const float* out_b   = (const float*)d_in[14];
    const int* ord_idx   = (const int*)d_in[15];
    const int* plus_idx  = (const int*)d_in[16];
    const int* minus_idx = (const int*)d_in[17];

    float* ws  = (float*)d_ws;
    float* h1T = ws;                      //   8192 f
    float* h2  = h1T + 8192;              // 2097664 f  [2][16][16][4097]
    float* t0  = h2 + 2097664;            // 8389120 f  [2][16][16][16385]
    float* t1  = t0 + 8389120;            // 2097152 f  [2][16][65536]
    float* out = (float*)d_out;

    hipLaunchKernelGGL(fc1_kernel, dim3(32), dim3(256), 0, stream, x, W1, b1, h1T);
    hipLaunchKernelGGL(fc2_kernel, dim3((NROWS + 255) / 256), dim3(256), 0, stream,
                       W2, b2, h1T, h2);
    hipLaunchKernelGGL(conv0_kernel, dim3(129, 16, 2), dim3(256), 0, stream,
                       h2, ctw0, ctb0, t0);
    hipLaunchKernelGGL(conv1_kernel, dim3(32, 16, 2), dim3(256), 0, stream,
                       t0, ctw1, ctb1, t1);
    hipLaunchKernelGGL(final_kernel, dim3(4096), dim3(256), 0, stream,
                       t1, sps_w, sps_b, final_w, final_b, out_w, out_b,
                       ord_idx, plus_idx, minus_idx, out);
}

// Round 2
// 568.442 us; speedup vs baseline: 1.5447x; 1.5447x over previous
//
#include <hip/hip_runtime.h>
#include <hip/hip_bf16.h>

// Sizes from the reference
#define N_NODES 65536
#define CFCH 16
#define L0LEN 4097
#define L1LEN 16385
#define NSFC 2
#define LATD 128
#define HIDD 512
#define NROWS (CFCH * L0LEN * NSFC)   // 131104

__device__ __forceinline__ float fast_tanh(float x) {
    float ax = fabsf(x);
    float e = __expf(-2.0f * ax);          // v_exp_f32 path
    float r = (1.0f - e) / (1.0f + e);     // in [0,1), stable for all ax
    return copysignf(r, x);
}

// ---------------- fc1: h1T[j*16+b] = tanh(x[b,:]·W1[j,:] + b1[j]) ----------------
__global__ void fc1_kernel(const float* __restrict__ x, const float* __restrict__ W1,
                           const float* __restrict__ b1, float* __restrict__ h1T) {
    int tid = blockIdx.x * 256 + threadIdx.x;   // 8192 threads
    int b = tid & 15;
    int j = tid >> 4;
    const float* xr = x + b * LATD;
    const float* wr = W1 + j * LATD;
    float acc = 0.f;
#pragma unroll 8
    for (int k = 0; k < LATD; ++k) acc = fmaf(xr[k], wr[k], acc);
    h1T[(j << 4) + b] = fast_tanh(acc + b1[j]);
}

// ---------------- fc2: h2 = tanh(h1 @ W2^T + b2), scattered to [sfc][b][c][l] ----------------
__global__ void __launch_bounds__(256) fc2_kernel(const float* __restrict__ W2,
                                                  const float* __restrict__ b2,
                                                  const float* __restrict__ h1T,
                                                  float* __restrict__ h2) {
    __shared__ float hS[HIDD * 16];   // 32 KB, layout [k][b]
    for (int idx = threadIdx.x; idx < HIDD * 16; idx += 256) hS[idx] = h1T[idx];
    __syncthreads();

    int j = blockIdx.x * 256 + threadIdx.x;
    if (j >= NROWS) j = NROWS - 1;    // clamp (uniform control flow; dup writes same value)

    const float4* wrow = (const float4*)(W2 + (size_t)j * HIDD);
    float acc[16];
#pragma unroll
    for (int b = 0; b < 16; ++b) acc[b] = 0.f;

#pragma unroll 1
    for (int k0 = 0; k0 < HIDD / 8; ++k0) {
        float4 wa = wrow[k0 * 2];
        float4 wb = wrow[k0 * 2 + 1];
        float w[8] = {wa.x, wa.y, wa.z, wa.w, wb.x, wb.y, wb.z, wb.w};
#pragma unroll
        for (int kk = 0; kk < 8; ++kk) {
            const float4* hp = (const float4*)&hS[((k0 * 8 + kk) << 4)];
            float4 ha = hp[0], hb = hp[1], hc = hp[2], hd = hp[3];
            float wv = w[kk];
            acc[0]  = fmaf(wv, ha.x, acc[0]);
            acc[1]  = fmaf(wv, ha.y, acc[1]);
            acc[2]  = fmaf(wv, ha.z, acc[2]);
            acc[3]  = fmaf(wv, ha.w, acc[3]);
            acc[4]  = fmaf(wv, hb.x, acc[4]);
            acc[5]  = fmaf(wv, hb.y, acc[5]);
            acc[6]  = fmaf(wv, hb.z, acc[6]);
            acc[7]  = fmaf(wv, hb.w, acc[7]);
            acc[8]  = fmaf(wv, hc.x, acc[8]);
            acc[9]  = fmaf(wv, hc.y, acc[9]);
            acc[10] = fmaf(wv, hc.z, acc[10]);
            acc[11] = fmaf(wv, hc.w, acc[11]);
            acc[12] = fmaf(wv, hd.x, acc[12]);
            acc[13] = fmaf(wv, hd.y, acc[13]);
            acc[14] = fmaf(wv, hd.z, acc[14]);
            acc[15] = fmaf(wv, hd.w, acc[15]);
        }
    }
    float bias = b2[j];
    int i = j & 1;
    int s = j >> 1;
    int c = s / L0LEN;
    int l = s - c * L0LEN;
#pragma unroll
    for (int b = 0; b < 16; ++b) {
        h2[(((size_t)(i * 16 + b) * CFCH + c) * L0LEN) + l] = fast_tanh(acc[b] + bias);
    }
}

// ---------------- conv0: ConvTranspose1d(16->16, K=32, s=4, p=16, op=1) + tanh ----------------
// out[o] = sum_ci sum_t w[ci][co][r+4t]*in[ci][q0-t],  r=o&3, q0=o/4+4
// wave = r (uniform -> scalar weight loads), lane = output chunk, blockIdx.z -> (i, co pair)
__global__ void __launch_bounds__(256, 4) conv0_kernel(const float* __restrict__ h2,
                                                       const float* __restrict__ ctw0,
                                                       const float* __restrict__ ctb0,
                                                       float* __restrict__ t0) {
    __shared__ float inS[16 * 528];   // [ci][window 528], stride 528 (16B-aligned rows)
    int bx = blockIdx.x, bb = blockIdx.y, z = blockIdx.z;
    int i = z >> 3;
    int co0 = (z & 7) << 1;
    int tid = threadIdx.x;
    int r = __builtin_amdgcn_readfirstlane(tid >> 6);  // wave-uniform phase
    int lane = tid & 63;

    const float* hin = h2 + (size_t)((i * 16 + bb) * 16) * L0LEN;
    int qbase = (bx << 9) - 4;
#pragma unroll 1
    for (int ci = 0; ci < 16; ++ci) {
        for (int x = tid; x < 528; x += 256) {
            int q = qbase + x;
            inS[ci * 528 + x] = (q >= 0 && q < L0LEN) ? hin[ci * L0LEN + q] : 0.f;
        }
    }
    __syncthreads();

    float acc0[8], acc1[8];
#pragma unroll
    for (int u = 0; u < 8; ++u) { acc0[u] = 0.f; acc1[u] = 0.f; }

    // weights: ctw0[i][ci][co][r+4t] -> wave-uniform pointer => s_load
    const float* wbase = ctw0 + (((i * 16) * 16 + co0) << 5) + r;
#pragma unroll 2
    for (int ci = 0; ci < 16; ++ci) {
        const float4* xp = (const float4*)&inS[ci * 528 + (lane << 3)];
        float4 xa = xp[0], xb = xp[1], xc = xp[2], xd = xp[3];
        float xin[16] = {xa.x, xa.y, xa.z, xa.w, xb.x, xb.y, xb.z, xb.w,
                         xc.x, xc.y, xc.z, xc.w, xd.x, xd.y, xd.z, xd.w};
        const float* w0 = wbase + ci * 512;   // (i,ci) stride = 16*32 floats
        const float* w1 = w0 + 32;
#pragma unroll
        for (int t = 0; t < 8; ++t) {
            float wv0 = w0[t << 2];
            float wv1 = w1[t << 2];
#pragma unroll
            for (int u = 0; u < 8; ++u) {
                float xv = xin[u - t + 8];
                acc0[u] = fmaf(wv0, xv, acc0[u]);
                acc1[u] = fmaf(wv1, xv, acc1[u]);
            }
        }
    }
    float b0 = ctb0[i * 16 + co0];
    float b1 = ctb0[i * 16 + co0 + 1];
    int o0 = bx << 11;
    float* dst0 = t0 + ((size_t)(i * 16 + bb) * 16 + co0) * L1LEN;
    float* dst1 = dst0 + L1LEN;
#pragma unroll
    for (int u = 0; u < 8; ++u) {
        int o = o0 + (((lane << 3) + u) << 2) + r;
        if (o < L1LEN) {
            dst0[o] = fast_tanh(acc0[u] + b0);
            dst1[o] = fast_tanh(acc1[u] + b1);
        }
    }
}

// ---------------- conv1: ConvTranspose1d(16->1, K=32, s=4, p=16, op=0) + tanh ----------------
__global__ void __launch_bounds__(256, 4) conv1_kernel(const float* __restrict__ t0,
                                                       const float* __restrict__ ctw1,
                                                       const float* __restrict__ ctb1,
                                                       float* __restrict__ t1) {
    __shared__ float inS[16 * 528];
    int bx = blockIdx.x, bb = blockIdx.y, i = blockIdx.z;
    int tid = threadIdx.x;
    int r = __builtin_amdgcn_readfirstlane(tid >> 6);
    int lane = tid & 63;

    const float* tin = t0 + (size_t)(i * 16 + bb) * 16 * L1LEN;
    int qbase = (bx << 9) - 4;
#pragma unroll 1
    for (int ci = 0; ci < 16; ++ci) {
        for (int x = tid; x < 528; x += 256) {
            int q = qbase + x;
            inS[ci * 528 + x] = (q >= 0 && q < L1LEN) ? tin[ci * L1LEN + q] : 0.f;
        }
    }
    __syncthreads();

    float acc[8];
#pragma unroll
    for (int u = 0; u < 8; ++u) acc[u] = 0.f;

    const float* wbase = ctw1 + ((i * 16) << 5) + r;
#pragma unroll 2
    for (int ci = 0; ci < 16; ++ci) {
        const float4* xp = (const float4*)&inS[ci * 528 + (lane << 3)];
        float4 xa = xp[0], xb = xp[1], xc = xp[2], xd = xp[3];
        float xin[16] = {xa.x, xa.y, xa.z, xa.w, xb.x, xb.y, xb.z, xb.w,
                         xc.x, xc.y, xc.z, xc.w, xd.x, xd.y, xd.z, xd.w};
        const float* w0 = wbase + (ci << 5);
#pragma unroll
        for (int t = 0; t < 8; ++t) {
            float wv = w0[t << 2];
#pragma unroll
            for (int u = 0; u < 8; ++u)
                acc[u] = fmaf(wv, xin[u - t + 8], acc[u]);
        }
    }
    float bias = ctb1[i];
    int o0 = bx << 11;
    float* dst = t1 + (size_t)(i * 16 + bb) * (size_t)N_NODES;
#pragma unroll
    for (int u = 0; u < 8; ++u) {
        int o = o0 + (((lane << 3) + u) << 2) + r;
        dst[o] = fast_tanh(acc[u] + bias);
    }
}

// ---------------- gather + per-sfc NN + final NN + output linear ----------------
__global__ void final_kernel(const float* __restrict__ t1,
                             const float* __restrict__ sps_w, const float* __restrict__ sps_b,
                             const float* __restrict__ final_w, const float* __restrict__ final_b,
                             const float* __restrict__ out_w, const float* __restrict__ out_b,
                             const int* __restrict__ ord_idx, const int* __restrict__ plus_idx,
                             const int* __restrict__ minus_idx, float* __restrict__ out) {
    int g = blockIdx.x * 256 + threadIdx.x;   // 16*65536 threads
    int b = g >> 16;
    int n = g & 65535;
    float z[2];
#pragma unroll
    for (int i = 0; i < 2; ++i) {
        int base = i * N_NODES + n;
        int im = minus_idx[base], io = ord_idx[base], ip = plus_idx[base];
        const float* tb = t1 + ((size_t)(i * 16 + b) << 16);
        float vm = tb[im], vo = tb[io], vp = tb[ip];
        const float* sw = sps_w + (size_t)base * 3;
        float s = fmaf(vm, sw[0], fmaf(vo, sw[1], vp * sw[2])) + sps_b[base];
        z[i] = fast_tanh(s);
    }
    float zz = fast_tanh(fmaf(z[0], final_w[n * 2], fmaf(z[1], final_w[n * 2 + 1], final_b[n])));
    out[g] = fmaf(zz, out_w[n], out_b[n]);
}

extern "C" void kernel_launch(void* const* d_in, const int* in_sizes, int n_in,
                              void* d_out, int out_size, void* d_ws, size_t ws_size,
                              hipStream_t stream) {
    const float* x       = (const float*)d_in[0];
    const float* W1      = (const float*)d_in[1];
    const float* b1      = (const float*)d_in[2];
    const float* W2      = (const float*)d_in[3];
    const float* b2      = (const float*)d_in[4];
    const float* ctw0    = (const float*)d_in[5];
    const float* ctb0    = (const float*)d_in[6];
    const float* ctw1    = (const float*)d_in[7];
    const float* ctb1    = (const float*)d_in[8];
    const float* sps_w   = (const float*)d_in[9];
    const float* sps_b   = (const float*)d_in[10];
    const float* final_w = (const float*)d_in[11];
    const float* final_b = (const float*)d_in[12];
    const float* out_w   = (const float*)d_in[13];
    const float* out_b   = (const float*)d_in[14];
    const int* ord_idx   = (const int*)d_in[15];
    const int* plus_idx  = (const int*)d_in[16];
    const int* minus_idx = (const int*)d_in[17];

    float* ws  = (float*)d_ws;
    float* h1T = ws;                      //   8192 f
    float* h2  = h1T + 8192;              // 2097664 f  [2][16][16][4097]
    float* t0  = h2 + 2097664;            // 8389120 f  [2][16][16][16385]
    float* t1  = t0 + 8389120;            // 2097152 f  [2][16][65536]
    float* out = (float*)d_out;

    hipLaunchKernelGGL(fc1_kernel, dim3(32), dim3(256), 0, stream, x, W1, b1, h1T);
    hipLaunchKernelGGL(fc2_kernel, dim3((NROWS + 255) / 256), dim3(256), 0, stream,
                       W2, b2, h1T, h2);
    hipLaunchKernelGGL(conv0_kernel, dim3(9, 16, 16), dim3(256), 0, stream,
                       h2, ctw0, ctb0, t0);
    hipLaunchKernelGGL(conv1_kernel, dim3(32, 16, 2), dim3(256), 0, stream,
                       t0, ctw1, ctb1, t1);
    hipLaunchKernelGGL(final_kernel, dim3(4096), dim3(256), 0, stream,
                       t1, sps_w, sps_b, final_w, final_b, out_w, out_b,
                       ord_idx, plus_idx, minus_idx, out);
}

// Round 3
// 553.103 us; speedup vs baseline: 1.5876x; 1.0277x over previous
//
#include <hip/hip_runtime.h>
#include <hip/hip_bf16.h>

// Sizes from the reference
#define N_NODES 65536
#define CFCH 16
#define L0LEN 4097
#define L1LEN 16385
#define NSFC 2
#define LATD 128
#define HIDD 512
#define NROWS (CFCH * L0LEN * NSFC)   // 131104

typedef __attribute__((ext_vector_type(8))) short short8;
typedef __attribute__((ext_vector_type(4))) float f32x4;

__device__ __forceinline__ float fast_tanh(float x) {
    float ax = fabsf(x);
    float e = __expf(-2.0f * ax);
    float r = (1.0f - e) / (1.0f + e);
    return copysignf(r, x);
}

__device__ __forceinline__ ushort f2bf(float f) {   // fp32 -> bf16 RNE
    unsigned u = __float_as_uint(f);
    return (ushort)((u + 0x7fffu + ((u >> 16) & 1u)) >> 16);
}

__device__ __forceinline__ void split8(const float4 a, const float4 b, short8& hi, short8& lo) {
    float f[8] = {a.x, a.y, a.z, a.w, b.x, b.y, b.z, b.w};
#pragma unroll
    for (int e = 0; e < 8; ++e) {
        ushort h = f2bf(f[e]);
        hi[e] = (short)h;
        lo[e] = (short)f2bf(f[e] - __uint_as_float((unsigned)h << 16));
    }
}

// ---------------- fc1: h[b][j] = tanh(x[b,:]·W1[j,:] + b1[j]) -> bf16 hi/lo [b][k] ----------------
__global__ void fc1_kernel(const float* __restrict__ x, const float* __restrict__ W1,
                           const float* __restrict__ b1,
                           ushort* __restrict__ h1hi, ushort* __restrict__ h1lo) {
    int tid = blockIdx.x * 256 + threadIdx.x;   // 8192 threads
    int b = tid & 15;
    int j = tid >> 4;
    const float* xr = x + b * LATD;
    const float* wr = W1 + j * LATD;
    float acc = 0.f;
#pragma unroll 8
    for (int k = 0; k < LATD; ++k) acc = fmaf(xr[k], wr[k], acc);
    float h = fast_tanh(acc + b1[j]);
    ushort hi = f2bf(h);
    float hif = __uint_as_float((unsigned)hi << 16);
    ushort lo = f2bf(h - hif);
    h1hi[b * HIDD + j] = hi;
    h1lo[b * HIDD + j] = lo;
}

// ---------------- fc2 via MFMA: C[j,b] = tanh(W2[j,:]·h[:,b] + b2[j]) ----------------
// M=NROWS, N=16(batch), K=512. A=W2 (split bf16 hi/lo from registers, coalesced 128B-line
// global reads). B=h fragments from LDS. 3-term split: hi*hi + hi*lo + lo*hi.
__global__ void __launch_bounds__(256, 4) fc2_kernel(const float* __restrict__ W2,
                                                     const float* __restrict__ b2,
                                                     const ushort* __restrict__ h1hi,
                                                     const ushort* __restrict__ h1lo,
                                                     float* __restrict__ h2) {
    __shared__ __align__(16) ushort hB[2][16][520];   // [hi/lo][n=batch][k] bf16, pad row to 520
    for (int u = threadIdx.x; u < 2048; u += 256) {
        int arr = u >> 10, uu = u & 1023;
        int n = uu >> 6, kc = uu & 63;                 // 64 x 16B units per row
        const ushort* src = (arr ? h1lo : h1hi) + n * HIDD + kc * 8;
        *(uint4*)&hB[arr][n][kc * 8] = *(const uint4*)src;
    }
    __syncthreads();

    int tid = threadIdx.x;
    int w = tid >> 6, lane = tid & 63;
    int lm = lane & 15, lq = lane >> 4;
    int j0 = blockIdx.x * 128;                         // 128 rows per block, 2 M-tiles per wave
    int jr0 = j0 + (w * 2) * 16 + lm;     if (jr0 >= NROWS) jr0 = NROWS - 1;
    int jr1 = j0 + (w * 2 + 1) * 16 + lm; if (jr1 >= NROWS) jr1 = NROWS - 1;
    const float* a0p = W2 + (size_t)jr0 * HIDD + lq * 8;   // A-frag: m=lane&15, k=(lane>>4)*8+e
    const float* a1p = W2 + (size_t)jr1 * HIDD + lq * 8;
    const ushort* bhp = &hB[0][lm][lq * 8];                // B-frag: n=lane&15, k=(lane>>4)*8+e
    const ushort* blp = &hB[1][lm][lq * 8];
    f32x4 acc0 = {0.f, 0.f, 0.f, 0.f};
    f32x4 acc1 = {0.f, 0.f, 0.f, 0.f};

#pragma unroll 2
    for (int ks = 0; ks < 16; ++ks) {                  // K-steps of 32
        float4 a0a = *(const float4*)(a0p + ks * 32);
        float4 a0b = *(const float4*)(a0p + ks * 32 + 4);
        float4 a1a = *(const float4*)(a1p + ks * 32);
        float4 a1b = *(const float4*)(a1p + ks * 32 + 4);
        short8 bh = *(const short8*)(bhp + ks * 32);
        short8 bl = *(const short8*)(blp + ks * 32);
        short8 h0, l0, h1v, l1v;
        split8(a0a, a0b, h0, l0);
        split8(a1a, a1b, h1v, l1v);
        acc0 = __builtin_amdgcn_mfma_f32_16x16x32_bf16(h0, bh, acc0, 0, 0, 0);
        acc1 = __builtin_amdgcn_mfma_f32_16x16x32_bf16(h1v, bh, acc1, 0, 0, 0);
        acc0 = __builtin_amdgcn_mfma_f32_16x16x32_bf16(h0, bl, acc0, 0, 0, 0);
        acc1 = __builtin_amdgcn_mfma_f32_16x16x32_bf16(h1v, bl, acc1, 0, 0, 0);
        acc0 = __builtin_amdgcn_mfma_f32_16x16x32_bf16(l0, bh, acc0, 0, 0, 0);
        acc1 = __builtin_amdgcn_mfma_f32_16x16x32_bf16(l1v, bh, acc1, 0, 0, 0);
    }

    // D layout: n(col)=lane&15, m(row)=(lane>>4)*4+reg  [measured m89/m91]
#pragma unroll
    for (int mt = 0; mt < 2; ++mt) {
        f32x4 acc = mt ? acc1 : acc0;
        int jb = j0 + (w * 2 + mt) * 16 + lq * 4;
#pragma unroll
        for (int reg = 0; reg < 4; ++reg) {
            int j = jb + reg;
            if (j < NROWS) {
                float val = fast_tanh(acc[reg] + b2[j]);
                int ii = j & 1;
                int s = j >> 1;
                int c = s / L0LEN;
                int l = s - c * L0LEN;
                h2[((size_t)(ii * 16 + lm) * CFCH + c) * L0LEN + l] = val;
            }
        }
    }
}

// Swizzled LDS addressing for conv inputs: pad 4 floats every 32 ->
// lane-stride-8-float f4 reads cover all 8 bank-quads per 8-lane group (conflict-free).
#define SROW 592
#define PHYSF(f) ((f) + (((f) >> 5) << 2))

// ---------------- conv0: ConvTranspose1d(16->16, K=32, s=4, p=16, op=1) + tanh ----------------
// out[o] = sum_ci sum_t w[ci][co][r+4t]*in[ci][q0-t],  r=o&3, q0=o/4+4
__global__ void __launch_bounds__(256, 4) conv0_kernel(const float* __restrict__ h2,
                                                       const float* __restrict__ ctw0,
                                                       const float* __restrict__ ctb0,
                                                       float* __restrict__ t0) {
    __shared__ float inS[16 * SROW];
    int bx = blockIdx.x, bb = blockIdx.y, z = blockIdx.z;
    int i = z >> 3;
    int co0 = (z & 7) << 1;
    int tid = threadIdx.x;
    int r = __builtin_amdgcn_readfirstlane(tid >> 6);  // wave-uniform phase
    int lane = tid & 63;

    const float* hin = h2 + (size_t)((i * 16 + bb) * 16) * L0LEN;
    int qbase = (bx << 9) - 4;
#pragma unroll 1
    for (int ci = 0; ci < 16; ++ci) {
        for (int xx = tid; xx < 528; xx += 256) {
            int q = qbase + xx;
            inS[ci * SROW + PHYSF(xx)] = (q >= 0 && q < L0LEN) ? hin[ci * L0LEN + q] : 0.f;
        }
    }
    __syncthreads();

    float acc0[8], acc1[8];
#pragma unroll
    for (int u = 0; u < 8; ++u) { acc0[u] = 0.f; acc1[u] = 0.f; }

    const float* wbase = ctw0 + (((i * 16) * 16 + co0) << 5) + r;  // wave-uniform -> s_load
    int fb = lane << 3;
#pragma unroll 2
    for (int ci = 0; ci < 16; ++ci) {
        int base = ci * SROW;
        float4 xa = *(const float4*)&inS[base + PHYSF(fb)];
        float4 xb = *(const float4*)&inS[base + PHYSF(fb + 4)];
        float4 xc = *(const float4*)&inS[base + PHYSF(fb + 8)];
        float4 xd = *(const float4*)&inS[base + PHYSF(fb + 12)];
        float xin[16] = {xa.x, xa.y, xa.z, xa.w, xb.x, xb.y, xb.z, xb.w,
                         xc.x, xc.y, xc.z, xc.w, xd.x, xd.y, xd.z, xd.w};
        const float* w0 = wbase + ci * 512;
        const float* w1 = w0 + 32;
#pragma unroll
        for (int t = 0; t < 8; ++t) {
            float wv0 = w0[t << 2];
            float wv1 = w1[t << 2];
#pragma unroll
            for (int u = 0; u < 8; ++u) {
                float xv = xin[u - t + 8];
                acc0[u] = fmaf(wv0, xv, acc0[u]);
                acc1[u] = fmaf(wv1, xv, acc1[u]);
            }
        }
    }
    float b0 = ctb0[i * 16 + co0];
    float b1 = ctb0[i * 16 + co0 + 1];
    int o0 = bx << 11;
    float* dst0 = t0 + ((size_t)(i * 16 + bb) * 16 + co0) * L1LEN;
    float* dst1 = dst0 + L1LEN;
#pragma unroll
    for (int u = 0; u < 8; ++u) {
        int o = o0 + (((lane << 3) + u) << 2) + r;
        if (o < L1LEN) {
            dst0[o] = fast_tanh(acc0[u] + b0);
            dst1[o] = fast_tanh(acc1[u] + b1);
        }
    }
}

// ---------------- conv1: ConvTranspose1d(16->1, K=32, s=4, p=16, op=0) + tanh ----------------
__global__ void __launch_bounds__(256, 4) conv1_kernel(const float* __restrict__ t0,
                                                       const float* __restrict__ ctw1,
                                                       const float* __restrict__ ctb1,
                                                       float* __restrict__ t1) {
    __shared__ float inS[16 * SROW];
    int bx = blockIdx.x, bb = blockIdx.y, i = blockIdx.z;
    int tid = threadIdx.x;
    int r = __builtin_amdgcn_readfirstlane(tid >> 6);
    int lane = tid & 63;

    const float* tin = t0 + (size_t)(i * 16 + bb) * 16 * L1LEN;
    int qbase = (bx << 9) - 4;
#pragma unroll 1
    for (int ci = 0; ci < 16; ++ci) {
        for (int xx = tid; xx < 528; xx += 256) {
            int q = qbase + xx;
            inS[ci * SROW + PHYSF(xx)] = (q >= 0 && q < L1LEN) ? tin[ci * L1LEN + q] : 0.f;
        }
    }
    __syncthreads();

    float acc[8];
#pragma unroll
    for (int u = 0; u < 8; ++u) acc[u] = 0.f;

    const float* wbase = ctw1 + ((i * 16) << 5) + r;
    int fb = lane << 3;
#pragma unroll 2
    for (int ci = 0; ci < 16; ++ci) {
        int base = ci * SROW;
        float4 xa = *(const float4*)&inS[base + PHYSF(fb)];
        float4 xb = *(const float4*)&inS[base + PHYSF(fb + 4)];
        float4 xc = *(const float4*)&inS[base + PHYSF(fb + 8)];
        float4 xd = *(const float4*)&inS[base + PHYSF(fb + 12)];
        float xin[16] = {xa.x, xa.y, xa.z, xa.w, xb.x, xb.y, xb.z, xb.w,
                         xc.x, xc.y, xc.z, xc.w, xd.x, xd.y, xd.z, xd.w};
        const float* w0 = wbase + (ci << 5);
#pragma unroll
        for (int t = 0; t < 8; ++t) {
            float wv = w0[t << 2];
#pragma unroll
            for (int u = 0; u < 8; ++u)
                acc[u] = fmaf(wv, xin[u - t + 8], acc[u]);
        }
    }
    float bias = ctb1[i];
    int o0 = bx << 11;
    float* dst = t1 + (size_t)(i * 16 + bb) * (size_t)N_NODES;
#pragma unroll
    for (int u = 0; u < 8; ++u) {
        int o = o0 + (((lane << 3) + u) << 2) + r;
        dst[o] = fast_tanh(acc[u] + bias);
    }
}

// ---------------- gather + per-sfc NN + final NN + output linear ----------------
// minus/plus are shifts of ord: minus[n]=ord[n-1] (n>0, else ord[0]), plus[n]=ord[n+1] (n<N-1, else ord[N-1])
__global__ void __launch_bounds__(256) final_kernel(const float* __restrict__ t1,
        const float* __restrict__ sps_w, const float* __restrict__ sps_b,
        const float* __restrict__ final_w, const float* __restrict__ final_b,
        const float* __restrict__ out_w, const float* __restrict__ out_b,
        const int* __restrict__ ord_idx, float* __restrict__ out) {
    int g = blockIdx.x * 256 + threadIdx.x;   // 262144 threads
    int b = g >> 14;
    int n0 = (g & 16383) << 2;                // 4 nodes per thread
    float z[2][4];
#pragma unroll
    for (int i = 0; i < 2; ++i) {
        const int* od = ord_idx + i * N_NODES;
        int4 mid = *(const int4*)(od + n0);
        int idx0 = (n0 == 0) ? mid.x : od[n0 - 1];
        int idx5 = (n0 + 4 >= N_NODES) ? mid.w : od[n0 + 4];
        const float* tb = t1 + ((size_t)(i * 16 + b) << 16);
        float v0 = tb[idx0], v1 = tb[mid.x], v2 = tb[mid.y],
              v3 = tb[mid.z], v4 = tb[mid.w], v5 = tb[idx5];
        const float* sw = sps_w + ((size_t)i * N_NODES + n0) * 3;
        float4 swa = *(const float4*)sw;
        float4 swb = *(const float4*)(sw + 4);
        float4 swc = *(const float4*)(sw + 8);
        float4 sb = *(const float4*)(sps_b + (size_t)i * N_NODES + n0);
        z[i][0] = fast_tanh(fmaf(v0, swa.x, fmaf(v1, swa.y, fmaf(v2, swa.z, sb.x))));
        z[i][1] = fast_tanh(fmaf(v1, swa.w, fmaf(v2, swb.x, fmaf(v3, swb.y, sb.y))));
        z[i][2] = fast_tanh(fmaf(v2, swb.z, fmaf(v3, swb.w, fmaf(v4, swc.x, sb.z))));
        z[i][3] = fast_tanh(fmaf(v3, swc.y, fmaf(v4, swc.z, fmaf(v5, swc.w, sb.w))));
    }
    float4 fwa = *(const float4*)(final_w + (size_t)n0 * 2);
    float4 fwb = *(const float4*)(final_w + (size_t)n0 * 2 + 4);
    float4 fb = *(const float4*)(final_b + n0);
    float4 ow = *(const float4*)(out_w + n0);
    float4 ob = *(const float4*)(out_b + n0);
    float4 r;
    r.x = fmaf(fast_tanh(fmaf(z[0][0], fwa.x, fmaf(z[1][0], fwa.y, fb.x))), ow.x, ob.x);
    r.y = fmaf(fast_tanh(fmaf(z[0][1], fwa.z, fmaf(z[1][1], fwa.w, fb.y))), ow.y, ob.y);
    r.z = fmaf(fast_tanh(fmaf(z[0][2], fwb.x, fmaf(z[1][2], fwb.y, fb.z))), ow.z, ob.z);
    r.w = fmaf(fast_tanh(fmaf(z[0][3], fwb.z, fmaf(z[1][3], fwb.w, fb.w))), ow.w, ob.w);
    *(float4*)(out + ((size_t)b << 16) + n0) = r;
}

extern "C" void kernel_launch(void* const* d_in, const int* in_sizes, int n_in,
                              void* d_out, int out_size, void* d_ws, size_t ws_size,
                              hipStream_t stream) {
    const float* x       = (const float*)d_in[0];
    const float* W1      = (const float*)d_in[1];
    const float* b1      = (const float*)d_in[2];
    const float* W2      = (const float*)d_in[3];
    const float* b2      = (const float*)d_in[4];
    const float* ctw0    = (const float*)d_in[5];
    const float* ctb0    = (const float*)d_in[6];
    const float* ctw1    = (const float*)d_in[7];
    const float* ctb1    = (const float*)d_in[8];
    const float* sps_w   = (const float*)d_in[9];
    const float* sps_b   = (const float*)d_in[10];
    const float* final_w = (const float*)d_in[11];
    const float* final_b = (const float*)d_in[12];
    const float* out_w   = (const float*)d_in[13];
    const float* out_b   = (const float*)d_in[14];
    const int* ord_idx   = (const int*)d_in[15];

    float* ws  = (float*)d_ws;
    float* h2  = ws;                      // 2097664 f  [2][16][16][4097]
    float* t0  = h2 + 2097664;            // 8389120 f  [2][16][16][16385]
    float* t1  = t0 + 8389120;            // 2097152 f  [2][16][65536]
    ushort* h1hi = (ushort*)(t1 + 2097152);  // 8192 ushorts
    ushort* h1lo = h1hi + 8192;
    float* out = (float*)d_out;

    hipLaunchKernelGGL(fc1_kernel, dim3(32), dim3(256), 0, stream, x, W1, b1, h1hi, h1lo);
    hipLaunchKernelGGL(fc2_kernel, dim3((NROWS + 127) / 128), dim3(256), 0, stream,
                       W2, b2, h1hi, h1lo, h2);
    hipLaunchKernelGGL(conv0_kernel, dim3(9, 16, 16), dim3(256), 0, stream,
                       h2, ctw0, ctb0, t0);
    hipLaunchKernelGGL(conv1_kernel, dim3(32, 16, 2), dim3(256), 0, stream,
                       t0, ctw1, ctb1, t1);
    hipLaunchKernelGGL(final_kernel, dim3(1024), dim3(256), 0, stream,
                       t1, sps_w, sps_b, final_w, final_b, out_w, out_b,
                       ord_idx, out);
}